// Round 11
// baseline (156.361 us; speedup 1.0000x reference)
//
#include <hip/hip_runtime.h>

#define GAMMA 0.5f
#define SMOOTH 1.0f
#define MB_BLOCKS 2048
#define NCONTOUR 64
#define CHUNK 8

typedef float f32x4 __attribute__((ext_vector_type(4)));

// ---------------------------------------------------------------------------
// Mask-path body: single burst of 24 loads. g,s PLAIN (L3 retains them
// across graph replays -- R10 warm evidence: hbm_bytes 0.34 MB), c
// NONTEMPORAL (anchors the clustered burst schedule; all-plain variants
// collapsed to VGPR~32 interleave in R2/R4/R7, nt variants never did).
// Block partial sums folded into 5 global fp32 atomics (order-rounding
// irrelevant: output is a ratio of ~8e6-magnitude sums, threshold 3.38).
// ---------------------------------------------------------------------------
__device__ __attribute__((noinline)) void mask_sums_body(
    const f32x4* __restrict__ g4, const f32x4* __restrict__ s4,
    const f32x4* __restrict__ c4, float* __restrict__ sums, int mbid)
{
    int base = mbid * (256 * CHUNK) + threadIdx.x;

    f32x4 g[CHUNK], s[CHUNK], c[CHUNK];
#pragma unroll
    for (int k = 0; k < CHUNK; ++k) g[k] = g4[base + k * 256];
#pragma unroll
    for (int k = 0; k < CHUNK; ++k) s[k] = s4[base + k * 256];
#pragma unroll
    for (int k = 0; k < CHUNK; ++k)
        c[k] = __builtin_nontemporal_load(&c4[base + k * 256]);

    float s_cg = 0.f, s_cs = 0.f, s_c = 0.f, s_g = 0.f, s_s = 0.f;
#pragma unroll
    for (int k = 0; k < CHUNK; ++k) {
        s_cg += c[k].x * g[k].x + c[k].y * g[k].y + c[k].z * g[k].z + c[k].w * g[k].w;
        s_cs += c[k].x * s[k].x + c[k].y * s[k].y + c[k].z * s[k].z + c[k].w * s[k].w;
        s_c  += c[k].x + c[k].y + c[k].z + c[k].w;
        s_g  += g[k].x + g[k].y + g[k].z + g[k].w;
        s_s  += s[k].x + s[k].y + s[k].z + s[k].w;
    }

#pragma unroll
    for (int off = 32; off > 0; off >>= 1) {
        s_cg += __shfl_down(s_cg, off);
        s_cs += __shfl_down(s_cs, off);
        s_c  += __shfl_down(s_c,  off);
        s_g  += __shfl_down(s_g,  off);
        s_s  += __shfl_down(s_s,  off);
    }
    __shared__ float red[4][5];
    int lane = threadIdx.x & 63;
    int wid  = threadIdx.x >> 6;
    if (lane == 0) {
        red[wid][0] = s_cg; red[wid][1] = s_cs; red[wid][2] = s_c;
        red[wid][3] = s_g;  red[wid][4] = s_s;
    }
    __syncthreads();
    if (threadIdx.x == 0) {
#pragma unroll
        for (int k = 0; k < 5; ++k) {
            float a = red[0][k] + red[1][k] + red[2][k] + red[3][k];
            atomicAdd(&sums[k], a);
        }
    }
}

// ---------------------------------------------------------------------------
// Contour-path body: per-batch cyclic-shift MSE minima (one block = batch b).
// ---------------------------------------------------------------------------
__device__ __attribute__((noinline)) void contour_body(
    const float2* __restrict__ gtc, const float2* __restrict__ sgs,
    const float2* __restrict__ scs, const float2* __restrict__ cc,
    float* __restrict__ seg_min, float* __restrict__ cons_min, int b)
{
    __shared__ float gx[256], gy[256];   // ground_truth_contour
    __shared__ float ax[256], ay[256];   // snake_GT_size
    __shared__ float px[256], py[256];   // snake_classic_size
    __shared__ float cx[256], cy[256];   // classic_contour
    int t = threadIdx.x;
    float2 v;
    v = gtc[b * 256 + t]; gx[t] = v.x; gy[t] = v.y;
    v = sgs[b * 256 + t]; ax[t] = v.x; ay[t] = v.y;
    v = scs[b * 256 + t]; px[t] = v.x; py[t] = v.y;
    v = cc [b * 256 + t]; cx[t] = v.x; cy[t] = v.y;
    __syncthreads();

    // shift-0 seg candidate compares snake_classic_size vs GT contour
    const float* sx = (t == 0) ? px : ax;
    const float* sy = (t == 0) ? py : ay;

    float seg = 0.f, cons = 0.f;
#pragma unroll 4
    for (int j = 0; j < 256; ++j) {
        int r = (j - t) & 255;
        float dx = sx[j] - gx[r];
        float dy = sy[j] - gy[r];
        seg += dx * dx + dy * dy;
        float ex = px[j] - cx[r];
        float ey = py[j] - cy[r];
        cons += ex * ex + ey * ey;
    }
    seg  *= (1.0f / 512.0f);
    cons *= (1.0f / 512.0f);

#pragma unroll
    for (int off = 32; off > 0; off >>= 1) {
        seg  = fminf(seg,  __shfl_down(seg,  off));
        cons = fminf(cons, __shfl_down(cons, off));
    }
    __shared__ float rs[4], rc[4];
    int lane = t & 63, wid = t >> 6;
    if (lane == 0) { rs[wid] = seg; rc[wid] = cons; }
    __syncthreads();
    if (t == 0) {
        seg_min[b]  = fminf(fminf(rs[0], rs[1]), fminf(rs[2], rs[3]));
        cons_min[b] = fminf(fminf(rc[0], rc[1]), fminf(rc[2], rc[3]));
    }
}

// ---------------------------------------------------------------------------
// Kernel A (fused): blocks [0, NCONTOUR) do contour minima; blocks
// [NCONTOUR, NCONTOUR+MB_BLOCKS) do the 5-way mask sums (one burst each).
// __launch_bounds__(256, 4): 128-VGPR cap, no spill (R7/R8 lesson).
// ---------------------------------------------------------------------------
__global__ __launch_bounds__(256, 4) void fused_kernel(
    const f32x4* __restrict__ g4, const f32x4* __restrict__ s4,
    const f32x4* __restrict__ c4,
    const float2* __restrict__ gtc, const float2* __restrict__ sgs,
    const float2* __restrict__ scs, const float2* __restrict__ cc,
    float* __restrict__ sums, float* __restrict__ seg_min,
    float* __restrict__ cons_min)
{
    int bid = blockIdx.x;
    if (bid < NCONTOUR) {
        contour_body(gtc, sgs, scs, cc, seg_min, cons_min, bid);
    } else {
        mask_sums_body(g4, s4, c4, sums, bid - NCONTOUR);
    }
}

// ---------------------------------------------------------------------------
// Kernel B: finalize. One wave: sum the 64 seg/cons minima, read the 5
// atomic sums, compose the scalar loss.
// ---------------------------------------------------------------------------
__global__ __launch_bounds__(64) void final_kernel(
    const float* __restrict__ sums, const float* __restrict__ seg_min,
    const float* __restrict__ cons_min, float* __restrict__ out, int B)
{
    int t = threadIdx.x;
    float v5 = (t < B) ? seg_min[t]  : 0.f;
    float v6 = (t < B) ? cons_min[t] : 0.f;

#pragma unroll
    for (int off = 32; off > 0; off >>= 1) {
        v5 += __shfl_down(v5, off);
        v6 += __shfl_down(v6, off);
    }
    if (t == 0) {
        float S_cg = sums[0], S_cs = sums[1], S_c = sums[2],
              S_g  = sums[3], S_s  = sums[4];
        float dice1 = 1.f - (2.f * S_cg + SMOOTH) / (S_c + S_g + SMOOTH);
        float dice2 = 1.f - (2.f * S_cs + SMOOTH) / (S_c + S_s + SMOOTH);
        out[0] = dice1 + v5 + GAMMA * (dice2 + v6);
    }
}

extern "C" void kernel_launch(void* const* d_in, const int* in_sizes, int n_in,
                              void* d_out, int out_size, void* d_ws, size_t ws_size,
                              hipStream_t stream) {
    const float* gt_mask = (const float*)d_in[0];   // [B,512,512]
    const float* gtc     = (const float*)d_in[1];   // [B,256,2]
    const float* sgs     = (const float*)d_in[2];   // [B,256,2]
    const float* scs     = (const float*)d_in[3];   // [B,256,2]
    const float* sn_mask = (const float*)d_in[4];   // [B,512,512]
    const float* cc      = (const float*)d_in[5];   // [B,256,2]
    const float* cl_mask = (const float*)d_in[6];   // [B,512,512]
    float* out = (float*)d_out;

    int B = in_sizes[1] / 512;                      // 64

    float* ws       = (float*)d_ws;
    float* seg_min  = ws;                           // 64 floats
    float* cons_min = ws + 64;                      // 64 floats
    float* sums     = ws + 128;                     // 5 floats (atomic accum)

    // zero the 5 atomic accumulators every call (graph-capturable)
    hipMemsetAsync(sums, 0, 5 * sizeof(float), stream);

    hipLaunchKernelGGL(fused_kernel, dim3(MB_BLOCKS + NCONTOUR), dim3(256), 0, stream,
                       (const f32x4*)gt_mask, (const f32x4*)sn_mask,
                       (const f32x4*)cl_mask,
                       (const float2*)gtc, (const float2*)sgs,
                       (const float2*)scs, (const float2*)cc,
                       sums, seg_min, cons_min);
    hipLaunchKernelGGL(final_kernel, dim3(1), dim3(64), 0, stream,
                       sums, seg_min, cons_min, out, B);
}

// Round 12
// 36.612 us; speedup vs baseline: 4.2707x; 4.2707x over previous
//
#include <hip/hip_runtime.h>

#define GAMMA 0.5f
#define SMOOTH 1.0f
#define MB_BLOCKS 2048
#define NCONTOUR 64
#define CHUNK 8

typedef float f32x4 __attribute__((ext_vector_type(4)));

// ---------------------------------------------------------------------------
// Contour-path body: per-batch cyclic-shift MSE minima (one block = batch b).
// noinline keeps its regalloc/scheduling out of the mask path.
// ---------------------------------------------------------------------------
__device__ __attribute__((noinline)) void contour_body(
    const float2* __restrict__ gtc, const float2* __restrict__ sgs,
    const float2* __restrict__ scs, const float2* __restrict__ cc,
    float* __restrict__ seg_min, float* __restrict__ cons_min, int b)
{
    __shared__ float gx[256], gy[256];   // ground_truth_contour
    __shared__ float ax[256], ay[256];   // snake_GT_size
    __shared__ float px[256], py[256];   // snake_classic_size
    __shared__ float cx[256], cy[256];   // classic_contour
    int t = threadIdx.x;
    float2 v;
    v = gtc[b * 256 + t]; gx[t] = v.x; gy[t] = v.y;
    v = sgs[b * 256 + t]; ax[t] = v.x; ay[t] = v.y;
    v = scs[b * 256 + t]; px[t] = v.x; py[t] = v.y;
    v = cc [b * 256 + t]; cx[t] = v.x; cy[t] = v.y;
    __syncthreads();

    // shift-0 seg candidate compares snake_classic_size vs GT contour
    const float* sx = (t == 0) ? px : ax;
    const float* sy = (t == 0) ? py : ay;

    float seg = 0.f, cons = 0.f;
#pragma unroll 4
    for (int j = 0; j < 256; ++j) {
        int r = (j - t) & 255;
        float dx = sx[j] - gx[r];
        float dy = sy[j] - gy[r];
        seg += dx * dx + dy * dy;
        float ex = px[j] - cx[r];
        float ey = py[j] - cy[r];
        cons += ex * ex + ey * ey;
    }
    seg  *= (1.0f / 512.0f);
    cons *= (1.0f / 512.0f);

#pragma unroll
    for (int off = 32; off > 0; off >>= 1) {
        seg  = fminf(seg,  __shfl_down(seg,  off));
        cons = fminf(cons, __shfl_down(cons, off));
    }
    __shared__ float rs[4], rc[4];
    int lane = t & 63, wid = t >> 6;
    if (lane == 0) { rs[wid] = seg; rc[wid] = cons; }
    __syncthreads();
    if (t == 0) {
        seg_min[b]  = fminf(fminf(rs[0], rs[1]), fminf(rs[2], rs[3]));
        cons_min[b] = fminf(fminf(rc[0], rc[1]), fminf(rc[2], rc[3]));
    }
}

// ---------------------------------------------------------------------------
// Kernel A (fused): blocks [0, NCONTOUR) do contour minima; blocks
// [NCONTOUR, NCONTOUR+MB_BLOCKS) do the 5-way mask sums.
// Mask path (inlined): PLAIN loads (L3 retains all 201 MB across graph
// replays -- R2/R4/R10 warm evidence) + sched_group_barrier pin +
// amdgpu_waves_per_eu(4,4). R10-VERBATIM: best measured config (45.68us,
// VGPR=56, no spill, warm hbm_bytes 0.34 MB). DO NOT TOUCH.
// ---------------------------------------------------------------------------
__global__ __launch_bounds__(256)
__attribute__((amdgpu_waves_per_eu(4, 4)))
void fused_kernel(
    const f32x4* __restrict__ g4, const f32x4* __restrict__ s4,
    const f32x4* __restrict__ c4,
    const float2* __restrict__ gtc, const float2* __restrict__ sgs,
    const float2* __restrict__ scs, const float2* __restrict__ cc,
    float* __restrict__ psum, float* __restrict__ seg_min,
    float* __restrict__ cons_min)
{
    int bid = blockIdx.x;
    if (bid < NCONTOUR) {
        contour_body(gtc, sgs, scs, cc, seg_min, cons_min, bid);
        return;
    }

    int mbid = bid - NCONTOUR;
    int base = mbid * (256 * CHUNK) + threadIdx.x;

    f32x4 g[CHUNK], s[CHUNK], c[CHUNK];
#pragma unroll
    for (int k = 0; k < CHUNK; ++k) g[k] = g4[base + k * 256];
#pragma unroll
    for (int k = 0; k < CHUNK; ++k) s[k] = s4[base + k * 256];
#pragma unroll
    for (int k = 0; k < CHUNK; ++k) c[k] = c4[base + k * 256];

    float s_cg = 0.f, s_cs = 0.f, s_c = 0.f, s_g = 0.f, s_s = 0.f;
#pragma unroll
    for (int k = 0; k < CHUNK; ++k) {
        s_cg += c[k].x * g[k].x + c[k].y * g[k].y + c[k].z * g[k].z + c[k].w * g[k].w;
        s_cs += c[k].x * s[k].x + c[k].y * s[k].y + c[k].z * s[k].z + c[k].w * s[k].w;
        s_c  += c[k].x + c[k].y + c[k].z + c[k].w;
        s_g  += g[k].x + g[k].y + g[k].z + g[k].w;
        s_s  += s[k].x + s[k].y + s[k].z + s[k].w;
    }

    // T19 pin: addr VALU -> 24 VMEM_READ back-to-back -> FMA block.
    __builtin_amdgcn_sched_group_barrier(0x002, 16, 0);   // VALU (addr)
    __builtin_amdgcn_sched_group_barrier(0x020, 24, 0);   // VMEM_READ x24
    __builtin_amdgcn_sched_group_barrier(0x002, 200, 0);  // VALU (FMAs)

#pragma unroll
    for (int off = 32; off > 0; off >>= 1) {
        s_cg += __shfl_down(s_cg, off);
        s_cs += __shfl_down(s_cs, off);
        s_c  += __shfl_down(s_c,  off);
        s_g  += __shfl_down(s_g,  off);
        s_s  += __shfl_down(s_s,  off);
    }
    __shared__ float red[4][5];
    int lane = threadIdx.x & 63;
    int wid  = threadIdx.x >> 6;
    if (lane == 0) {
        red[wid][0] = s_cg; red[wid][1] = s_cs; red[wid][2] = s_c;
        red[wid][3] = s_g;  red[wid][4] = s_s;
    }
    __syncthreads();
    if (threadIdx.x == 0) {
#pragma unroll
        for (int k = 0; k < 5; ++k) {
            float a = red[0][k] + red[1][k] + red[2][k] + red[3][k];
            psum[k * MB_BLOCKS + mbid] = a;
        }
    }
}

// ---------------------------------------------------------------------------
// Kernel B: finalize. Vectorized f32x4 psum reads (isolated change vs R10;
// separate compilation, cannot perturb fused_kernel codegen), combined
// 7-value reduction, compose the scalar loss.
// ---------------------------------------------------------------------------
__global__ __launch_bounds__(256) void final_kernel(
    const float* __restrict__ psum, const float* __restrict__ seg_min,
    const float* __restrict__ cons_min, float* __restrict__ out, int B)
{
    int t = threadIdx.x;
    float v[7] = {0.f, 0.f, 0.f, 0.f, 0.f, 0.f, 0.f};

#pragma unroll
    for (int k = 0; k < 5; ++k) {
        const f32x4* p4 = (const f32x4*)(psum + k * MB_BLOCKS);
#pragma unroll
        for (int j = 0; j < MB_BLOCKS / 4 / 256; ++j) {
            f32x4 a = p4[j * 256 + t];
            v[k] += a.x + a.y + a.z + a.w;
        }
    }
    if (t < B) { v[5] = seg_min[t]; v[6] = cons_min[t]; }

#pragma unroll
    for (int off = 32; off > 0; off >>= 1) {
#pragma unroll
        for (int k = 0; k < 7; ++k) v[k] += __shfl_down(v[k], off);
    }
    __shared__ float red[4][7];
    int lane = t & 63, wid = t >> 6;
    if (lane == 0) {
#pragma unroll
        for (int k = 0; k < 7; ++k) red[wid][k] = v[k];
    }
    __syncthreads();
    if (t == 0) {
        float tot[7];
#pragma unroll
        for (int k = 0; k < 7; ++k)
            tot[k] = red[0][k] + red[1][k] + red[2][k] + red[3][k];
        float S_cg = tot[0], S_cs = tot[1], S_c = tot[2],
              S_g  = tot[3], S_s  = tot[4];
        float seg_tot = tot[5], cons_tot = tot[6];
        float dice1 = 1.f - (2.f * S_cg + SMOOTH) / (S_c + S_g + SMOOTH);
        float dice2 = 1.f - (2.f * S_cs + SMOOTH) / (S_c + S_s + SMOOTH);
        out[0] = dice1 + seg_tot + GAMMA * (dice2 + cons_tot);
    }
}

extern "C" void kernel_launch(void* const* d_in, const int* in_sizes, int n_in,
                              void* d_out, int out_size, void* d_ws, size_t ws_size,
                              hipStream_t stream) {
    const float* gt_mask = (const float*)d_in[0];   // [B,512,512]
    const float* gtc     = (const float*)d_in[1];   // [B,256,2]
    const float* sgs     = (const float*)d_in[2];   // [B,256,2]
    const float* scs     = (const float*)d_in[3];   // [B,256,2]
    const float* sn_mask = (const float*)d_in[4];   // [B,512,512]
    const float* cc      = (const float*)d_in[5];   // [B,256,2]
    const float* cl_mask = (const float*)d_in[6];   // [B,512,512]
    float* out = (float*)d_out;

    int B = in_sizes[1] / 512;                      // 64

    float* ws       = (float*)d_ws;
    float* psum     = ws;                           // 5 * MB_BLOCKS floats
    float* seg_min  = ws + 5 * MB_BLOCKS;           // B floats
    float* cons_min = seg_min + 64;                 // B floats

    hipLaunchKernelGGL(fused_kernel, dim3(MB_BLOCKS + NCONTOUR), dim3(256), 0, stream,
                       (const f32x4*)gt_mask, (const f32x4*)sn_mask,
                       (const f32x4*)cl_mask,
                       (const float2*)gtc, (const float2*)sgs,
                       (const float2*)scs, (const float2*)cc,
                       psum, seg_min, cons_min);
    hipLaunchKernelGGL(final_kernel, dim3(1), dim3(256), 0, stream,
                       psum, seg_min, cons_min, out, B);
}